// Round 6
// baseline (129.292 us; speedup 1.0000x reference)
//
#include <hip/hip_runtime.h>

// Poincare contrastive loss, N=4096, D=8, TEMP=0.5.
// sim[i][j] = 1/(1+arcosh(x_ij)), x_ij = 1 + 2*sqdist/((1-sqc_i)(1-sqc_j))
// Rewrite: x = 1 + P_i . Q_j  (10-term dot)
//   Q_j = [z_j(8), inv_j, inv_j*raw_j],  inv = 1/(1-min(raw,BOUNDARY))
//   P_i = [-4*inv_i*z_i(8), 2*inv_i*raw_i, 2*inv_i]
// loss = mean_i -(2*sim[i,partner] - log(sum_{j!=i} exp(2*sim[i][j])))
//
// SYMMETRY: e(i,j)=e(j,i); only tiles with jbase >= ibase do work. Grid is
// the full 8x256 rectangle (2048 blocks = exactly 8/CU); the 896 dead tiles
// early-exit and the HW dispatcher backfills -> dynamic load balance.
// Each pair (i<j) goes to denom[i] (register acc) and denom[j]
// (wave shfl_xor reduce -> LDS accumulator -> 1 atomic per (block,j)).
// Strict j>i mask on diagonal tiles excludes the self term exactly.

#define D 8
#define QS 12                // padded Q stride (floats) -> 48B, 16B-aligned
#define TWO_N 8192
#define HALF_N 4096
constexpr int BLOCK = 256;
constexpr int R     = 4;     // rows per thread -> i-tile = 1024
constexpr int JC    = 32;    // j-chunk staged in LDS per block
#define BOUNDARY (1.0f - 1e-5f)
#define LN2 0.6931471805599453f
#define TWO_LOG2E 2.8853900817779268f   // 2*log2(e)

__device__ __forceinline__ float frcp(float x)  { return __builtin_amdgcn_rcpf(x); }
__device__ __forceinline__ float fsqrt(float x) { return __builtin_amdgcn_sqrtf(x); }
__device__ __forceinline__ float flog2(float x) { return __builtin_amdgcn_logf(x); }
__device__ __forceinline__ float fexp2(float x) { return __builtin_amdgcn_exp2f(x); }

// ---- build Q[row] = [z(8), inv, inv*raw, 0, 0] ----
__global__ __launch_bounds__(256) void prep_kernel(
    const float* __restrict__ zi, const float* __restrict__ zj,
    float* __restrict__ q)
{
    const int row = blockIdx.x * 256 + threadIdx.x;
    const float* src = (row < HALF_N) ? (zi + (size_t)row * D)
                                      : (zj + (size_t)(row - HALF_N) * D);
    float4 a = *(const float4*)(src);
    float4 b = *(const float4*)(src + 4);
    float raw = a.x*a.x + a.y*a.y + a.z*a.z + a.w*a.w
              + b.x*b.x + b.y*b.y + b.z*b.z + b.w*b.w;
    float inv = frcp(1.0f - fminf(raw, BOUNDARY));
    float* dst = q + (size_t)row * QS;
    *(float4*)(dst)     = a;
    *(float4*)(dst + 4) = b;
    *(float4*)(dst + 8) = make_float4(inv, inv * raw, 0.0f, 0.0f);
}

// ---- symmetric pair kernel, rectangular grid with dead-tile early-exit ----
__global__ __launch_bounds__(BLOCK, 8) void pair_kernel(
    const float* __restrict__ q, float* __restrict__ denom)
{
    const int ibase = blockIdx.x * (BLOCK * R);   // 8 i-blocks of 1024 rows
    const int jbase = blockIdx.y * JC;            // 256 j-chunks of 32
    if (jbase < ibase) return;                    // dead tile: lower triangle
    const bool diag = (jbase < ibase + BLOCK * R);

    __shared__ float sq[JC * QS];       // 1.5 KB j-chunk Q
    __shared__ float sdenom[JC];        // column accumulators

    const int tid = threadIdx.x;

    // stage j-chunk Q (96 float4) + zero column accumulators
    if (tid < JC * QS / 4)
        ((float4*)sq)[tid] = ((const float4*)(q + (size_t)jbase * QS))[tid];
    if (tid < JC) sdenom[tid] = 0.0f;

    // own rows -> P in registers
    float p[R][10];
    float acc[R];
    int   irow[R];
    #pragma unroll
    for (int r = 0; r < R; ++r) {
        irow[r] = ibase + tid + r * BLOCK;
        const float* qr = q + (size_t)irow[r] * QS;
        float4 a  = *(const float4*)(qr);
        float4 bb = *(const float4*)(qr + 4);
        float4 c  = *(const float4*)(qr + 8);     // c.x=inv, c.y=inv*raw
        const float m = -4.0f * c.x;
        p[r][0] = m * a.x;  p[r][1] = m * a.y;  p[r][2] = m * a.z;  p[r][3] = m * a.w;
        p[r][4] = m * bb.x; p[r][5] = m * bb.y; p[r][6] = m * bb.z; p[r][7] = m * bb.w;
        p[r][8] = 2.0f * c.y;
        p[r][9] = 2.0f * c.x;
        acc[r] = 0.0f;
    }
    __syncthreads();

    #pragma unroll 2
    for (int jj = 0; jj < JC; ++jj) {
        const float* qq = sq + jj * QS;
        float4 a  = *(const float4*)(qq);         // broadcast, 16B-aligned
        float4 bb = *(const float4*)(qq + 4);
        float2 c  = *(const float2*)(qq + 8);
        const int j = jbase + jj;

        float ecol = 0.0f;
        #pragma unroll
        for (int r = 0; r < R; ++r) {
            float x = 1.0f;
            x = fmaf(p[r][0], a.x, x);  x = fmaf(p[r][1], a.y, x);
            x = fmaf(p[r][2], a.z, x);  x = fmaf(p[r][3], a.w, x);
            x = fmaf(p[r][4], bb.x, x); x = fmaf(p[r][5], bb.y, x);
            x = fmaf(p[r][6], bb.z, x); x = fmaf(p[r][7], bb.w, x);
            x = fmaf(p[r][8], c.x, x);  x = fmaf(p[r][9], c.y, x);
            float tt = fmaf(x, x, -1.0f);
            float s  = fsqrt(fmaxf(tt, 0.0f));
            float l  = flog2(x + s);
            float dd = fmaf(l, LN2, 1.0f);        // 1 + arcosh
            float sim = frcp(dd);
            float e  = fexp2(sim * TWO_LOG2E);    // exp(2*sim)
            if (diag) e = (j > irow[r]) ? e : 0.0f;   // strict upper triangle
            acc[r] += e;
            ecol   += e;
        }
        // wave reduction of ecol -> lane 0, then LDS accumulate for denom[j]
        #pragma unroll
        for (int m = 1; m < 64; m <<= 1)
            ecol += __shfl_xor(ecol, m, 64);
        if ((tid & 63) == 0) atomicAdd(&sdenom[jj], ecol);
    }

    __syncthreads();
    if (tid < JC) atomicAdd(&denom[jbase + tid], sdenom[tid]);
    #pragma unroll
    for (int r = 0; r < R; ++r)
        atomicAdd(&denom[irow[r]], acc[r]);
}

// ---- epilogue: one block, 1024 threads; denom already excludes self ----
__global__ __launch_bounds__(1024) void reduce_kernel(
    const float* __restrict__ zi, const float* __restrict__ zj,
    const float* __restrict__ denom, float* __restrict__ out)
{
    __shared__ float s_red[1024];
    const int tid = threadIdx.x;
    float acc = 0.0f;
    for (int i = tid; i < TWO_N; i += 1024) {
        const int base = (i < HALF_N) ? i : (i - HALF_N);
        const float* pa = (i < HALF_N) ? (zi + (size_t)base * D) : (zj + (size_t)base * D);
        const float* pb = (i < HALF_N) ? (zj + (size_t)base * D) : (zi + (size_t)base * D);
        float4 a0 = *(const float4*)(pa), a1 = *(const float4*)(pa + 4);
        float4 b0 = *(const float4*)(pb), b1 = *(const float4*)(pb + 4);
        float rawa = a0.x*a0.x + a0.y*a0.y + a0.z*a0.z + a0.w*a0.w
                   + a1.x*a1.x + a1.y*a1.y + a1.z*a1.z + a1.w*a1.w;
        float rawb = b0.x*b0.x + b0.y*b0.y + b0.z*b0.z + b0.w*b0.w
                   + b1.x*b1.x + b1.y*b1.y + b1.z*b1.z + b1.w*b1.w;
        float dot  = a0.x*b0.x + a0.y*b0.y + a0.z*b0.z + a0.w*b0.w
                   + a1.x*b1.x + a1.y*b1.y + a1.z*b1.z + a1.w*b1.w;
        float sqd  = fmaxf(rawa + rawb - 2.0f * dot, 0.0f);
        float inva = frcp(1.0f - fminf(rawa, BOUNDARY));
        float invb = frcp(1.0f - fminf(rawb, BOUNDARY));
        float x    = fmaf(2.0f * sqd, inva * invb, 1.0f);
        float t    = fmaf(x, x, -1.0f);
        float s    = fsqrt(fmaxf(t, 0.0f));
        float dist = flog2(x + s) * LN2;
        float sim  = frcp(1.0f + dist);           // positive pair similarity
        float dlog = flog2(denom[i]) * LN2;       // self already excluded
        acc += -(2.0f * sim - dlog);
    }
    s_red[tid] = acc;
    __syncthreads();
    for (int off = 512; off > 0; off >>= 1) {
        if (tid < off) s_red[tid] += s_red[tid + off];
        __syncthreads();
    }
    if (tid == 0) out[0] = s_red[0] * (1.0f / (float)TWO_N);
}

extern "C" void kernel_launch(void* const* d_in, const int* in_sizes, int n_in,
                              void* d_out, int out_size, void* d_ws, size_t ws_size,
                              hipStream_t stream) {
    const float* zi = (const float*)d_in[0];
    const float* zj = (const float*)d_in[1];

    float* denom = (float*)d_ws;                  // [8192]
    float* q     = denom + TWO_N;                 // [8192 * 12]

    hipMemsetAsync(denom, 0, (size_t)TWO_N * sizeof(float), stream);

    prep_kernel<<<TWO_N / 256, 256, 0, stream>>>(zi, zj, q);

    dim3 grid(TWO_N / (BLOCK * R), TWO_N / JC);   // 8 x 256 = 2048, 896 dead
    pair_kernel<<<grid, BLOCK, 0, stream>>>(q, denom);

    reduce_kernel<<<1, 1024, 0, stream>>>(zi, zj, denom, (float*)d_out);
}

// Round 7
// 106.993 us; speedup vs baseline: 1.2084x; 1.2084x over previous
//
#include <hip/hip_runtime.h>

// Poincare contrastive loss, N=4096, D=8, TEMP=0.5.
// sim[i][j] = 1/(1+arcosh(x_ij)), x_ij = 1 + 2*sqdist/((1-sqc_i)(1-sqc_j))
// Rewrite: x = 1 + P_i . Q_j  (10-term dot)
//   Q_j = [z_j(8), inv_j, inv_j*raw_j],  inv = 1/(1-min(raw,BOUNDARY))
//   P_i = [-4*inv_i*z_i(8), 2*inv_i*raw_i, 2*inv_i]
// loss = mean_i -(2*sim[i,partner] - log(sum_{j!=i} exp(2*sim[i][j])))
//
// SYMMETRY: e(i,j)=e(j,i). PACKED upper-triangle grid of 2176 tiles
// (i-tile 512 = 256 thr x R=2, j-chunk 32). 2176 = 8.5 blocks/CU ->
// full 32-wave residency + small backfill tail (round-6 lesson: an
// exactly-resident grid has static assignment; packed+oversubscribed wins).
// Tile decode: b = #{k : t >= F(k)}, F(k) = 256k - 8k(k-1), 15 uniform cmps.
// Each pair (i<j) -> denom[i] (register acc) and denom[j]
// (wave shfl_xor reduce -> LDS accumulator -> 1 atomic per (block,j)).
// Strict j>i mask on diagonal tiles excludes the self term exactly.

#define D 8
#define QS 12                // padded Q stride (floats) -> 48B, 16B-aligned
#define TWO_N 8192
#define HALF_N 4096
constexpr int BLOCK = 256;
constexpr int R     = 2;     // rows per thread -> i-tile = 512
constexpr int JC    = 32;    // j-chunk staged in LDS per block
constexpr int NTILE = 2176;  // sum_{b=0}^{15} (256 - 16b)
#define BOUNDARY (1.0f - 1e-5f)
#define LN2 0.6931471805599453f
#define TWO_LOG2E 2.8853900817779268f   // 2*log2(e)

__device__ __forceinline__ float frcp(float x)  { return __builtin_amdgcn_rcpf(x); }
__device__ __forceinline__ float fsqrt(float x) { return __builtin_amdgcn_sqrtf(x); }
__device__ __forceinline__ float flog2(float x) { return __builtin_amdgcn_logf(x); }
__device__ __forceinline__ float fexp2(float x) { return __builtin_amdgcn_exp2f(x); }

// ---- build Q[row] = [z(8), inv, inv*raw, 0, 0] ----
__global__ __launch_bounds__(256) void prep_kernel(
    const float* __restrict__ zi, const float* __restrict__ zj,
    float* __restrict__ q)
{
    const int row = blockIdx.x * 256 + threadIdx.x;
    const float* src = (row < HALF_N) ? (zi + (size_t)row * D)
                                      : (zj + (size_t)(row - HALF_N) * D);
    float4 a = *(const float4*)(src);
    float4 b = *(const float4*)(src + 4);
    float raw = a.x*a.x + a.y*a.y + a.z*a.z + a.w*a.w
              + b.x*b.x + b.y*b.y + b.z*b.z + b.w*b.w;
    float inv = frcp(1.0f - fminf(raw, BOUNDARY));
    float* dst = q + (size_t)row * QS;
    *(float4*)(dst)     = a;
    *(float4*)(dst + 4) = b;
    *(float4*)(dst + 8) = make_float4(inv, inv * raw, 0.0f, 0.0f);
}

// ---- symmetric pair kernel, packed upper-triangle tiles ----
__global__ __launch_bounds__(BLOCK, 8) void pair_kernel(
    const float* __restrict__ q, float* __restrict__ denom)
{
    __shared__ float sq[JC * QS];       // 1.5 KB j-chunk Q
    __shared__ float sdenom[JC];        // column accumulators

    const int tid = threadIdx.x;

    // tile decode: t -> (b = i-block of 512 rows, jbase)
    const int t = blockIdx.x;
    int b = 0;
    #pragma unroll
    for (int k = 1; k < 16; ++k)
        b += (t >= (256 * k - 8 * k * (k - 1))) ? 1 : 0;
    const int Fb    = 256 * b - 8 * b * (b - 1);
    const int ibase = 512 * b;
    const int jbase = ibase + 32 * (t - Fb);      // jc = 16b + (t-Fb)
    const bool diag = (jbase < ibase + BLOCK * R);

    // stage j-chunk Q (96 float4) + zero column accumulators
    if (tid < JC * QS / 4)
        ((float4*)sq)[tid] = ((const float4*)(q + (size_t)jbase * QS))[tid];
    if (tid < JC) sdenom[tid] = 0.0f;

    // own rows -> P in registers
    float p[R][10];
    float acc[R];
    int   irow[R];
    #pragma unroll
    for (int r = 0; r < R; ++r) {
        irow[r] = ibase + tid + r * BLOCK;
        const float* qr = q + (size_t)irow[r] * QS;
        float4 a  = *(const float4*)(qr);
        float4 bb = *(const float4*)(qr + 4);
        float4 c  = *(const float4*)(qr + 8);     // c.x=inv, c.y=inv*raw
        const float m = -4.0f * c.x;
        p[r][0] = m * a.x;  p[r][1] = m * a.y;  p[r][2] = m * a.z;  p[r][3] = m * a.w;
        p[r][4] = m * bb.x; p[r][5] = m * bb.y; p[r][6] = m * bb.z; p[r][7] = m * bb.w;
        p[r][8] = 2.0f * c.y;
        p[r][9] = 2.0f * c.x;
        acc[r] = 0.0f;
    }
    __syncthreads();

    #pragma unroll 4
    for (int jj = 0; jj < JC; ++jj) {
        const float* qq = sq + jj * QS;
        float4 a  = *(const float4*)(qq);         // broadcast, 16B-aligned
        float4 bb = *(const float4*)(qq + 4);
        float2 c  = *(const float2*)(qq + 8);
        const int j = jbase + jj;

        float ecol = 0.0f;
        #pragma unroll
        for (int r = 0; r < R; ++r) {
            float x = 1.0f;
            x = fmaf(p[r][0], a.x, x);  x = fmaf(p[r][1], a.y, x);
            x = fmaf(p[r][2], a.z, x);  x = fmaf(p[r][3], a.w, x);
            x = fmaf(p[r][4], bb.x, x); x = fmaf(p[r][5], bb.y, x);
            x = fmaf(p[r][6], bb.z, x); x = fmaf(p[r][7], bb.w, x);
            x = fmaf(p[r][8], c.x, x);  x = fmaf(p[r][9], c.y, x);
            float tt = fmaf(x, x, -1.0f);
            float s  = fsqrt(fmaxf(tt, 0.0f));
            float l  = flog2(x + s);
            float dd = fmaf(l, LN2, 1.0f);        // 1 + arcosh
            float sim = frcp(dd);
            float e  = fexp2(sim * TWO_LOG2E);    // exp(2*sim)
            if (diag) e = (j > irow[r]) ? e : 0.0f;   // strict upper triangle
            acc[r] += e;
            ecol   += e;
        }
        // wave reduction of ecol -> lane 0, then LDS accumulate for denom[j]
        #pragma unroll
        for (int m = 1; m < 64; m <<= 1)
            ecol += __shfl_xor(ecol, m, 64);
        if ((tid & 63) == 0) atomicAdd(&sdenom[jj], ecol);
    }

    __syncthreads();
    if (tid < JC) atomicAdd(&denom[jbase + tid], sdenom[tid]);
    #pragma unroll
    for (int r = 0; r < R; ++r)
        atomicAdd(&denom[irow[r]], acc[r]);
}

// ---- epilogue: one block, 1024 threads; denom already excludes self ----
__global__ __launch_bounds__(1024) void reduce_kernel(
    const float* __restrict__ zi, const float* __restrict__ zj,
    const float* __restrict__ denom, float* __restrict__ out)
{
    __shared__ float s_red[1024];
    const int tid = threadIdx.x;
    float acc = 0.0f;
    for (int i = tid; i < TWO_N; i += 1024) {
        const int base = (i < HALF_N) ? i : (i - HALF_N);
        const float* pa = (i < HALF_N) ? (zi + (size_t)base * D) : (zj + (size_t)base * D);
        const float* pb = (i < HALF_N) ? (zj + (size_t)base * D) : (zi + (size_t)base * D);
        float4 a0 = *(const float4*)(pa), a1 = *(const float4*)(pa + 4);
        float4 b0 = *(const float4*)(pb), b1 = *(const float4*)(pb + 4);
        float rawa = a0.x*a0.x + a0.y*a0.y + a0.z*a0.z + a0.w*a0.w
                   + a1.x*a1.x + a1.y*a1.y + a1.z*a1.z + a1.w*a1.w;
        float rawb = b0.x*b0.x + b0.y*b0.y + b0.z*b0.z + b0.w*b0.w
                   + b1.x*b1.x + b1.y*b1.y + b1.z*b1.z + b1.w*b1.w;
        float dot  = a0.x*b0.x + a0.y*b0.y + a0.z*b0.z + a0.w*b0.w
                   + a1.x*b1.x + a1.y*b1.y + a1.z*b1.z + a1.w*b1.w;
        float sqd  = fmaxf(rawa + rawb - 2.0f * dot, 0.0f);
        float inva = frcp(1.0f - fminf(rawa, BOUNDARY));
        float invb = frcp(1.0f - fminf(rawb, BOUNDARY));
        float x    = fmaf(2.0f * sqd, inva * invb, 1.0f);
        float t    = fmaf(x, x, -1.0f);
        float s    = fsqrt(fmaxf(t, 0.0f));
        float dist = flog2(x + s) * LN2;
        float sim  = frcp(1.0f + dist);           // positive pair similarity
        float dlog = flog2(denom[i]) * LN2;       // self already excluded
        acc += -(2.0f * sim - dlog);
    }
    s_red[tid] = acc;
    __syncthreads();
    for (int off = 512; off > 0; off >>= 1) {
        if (tid < off) s_red[tid] += s_red[tid + off];
        __syncthreads();
    }
    if (tid == 0) out[0] = s_red[0] * (1.0f / (float)TWO_N);
}

extern "C" void kernel_launch(void* const* d_in, const int* in_sizes, int n_in,
                              void* d_out, int out_size, void* d_ws, size_t ws_size,
                              hipStream_t stream) {
    const float* zi = (const float*)d_in[0];
    const float* zj = (const float*)d_in[1];

    float* denom = (float*)d_ws;                  // [8192]
    float* q     = denom + TWO_N;                 // [8192 * 12]

    hipMemsetAsync(denom, 0, (size_t)TWO_N * sizeof(float), stream);

    prep_kernel<<<TWO_N / 256, 256, 0, stream>>>(zi, zj, q);

    pair_kernel<<<NTILE, BLOCK, 0, stream>>>(q, denom);

    reduce_kernel<<<1, 1024, 0, stream>>>(zi, zj, denom, (float*)d_out);
}

// Round 8
// 100.443 us; speedup vs baseline: 1.2872x; 1.0652x over previous
//
#include <hip/hip_runtime.h>

// Poincare contrastive loss, N=4096, D=8, TEMP=0.5.
// sim[i][j] = 1/(1+arcosh(x_ij)), x_ij = 1 + 2*sqdist/((1-sqc_i)(1-sqc_j))
// Rewrite: x = 1 + P_i . Q_j  (10-term dot)
//   Q_j = [z_j(8), inv_j, inv_j*raw_j],  inv = 1/(1-min(raw,BOUNDARY))
//   P_i = [-4*inv_i*z_i(8), 2*inv_i*raw_i, 2*inv_i]
// loss = mean_i -(2*sim[i,partner] - log(sum_{j!=i} exp(2*sim[i][j])))
//
// SYMMETRY: packed upper-triangle grid of 2176 tiles (i-tile 512 = 256thr x
// R=2, j-chunk 32) -> 8.5 blocks/CU, full residency + backfill.
// PACKED FP32: the two rows per thread are one float2 lane-pair; all
// full-rate math uses v_pk_fma_f32-class VOP3P ops (2x fp32 rate on gfx950).
// Trans ops (sqrt/log2/rcp/exp2) remain scalar x2 - no pk form exists.
// Each pair (i<j) -> denom[i] (register acc) and denom[j]
// (wave shfl_xor reduce -> LDS accumulator -> 1 atomic per (block,j)).
// 3 stream ops: prep (also zeroes denom+out) -> pair -> reduce (8 blocks).

#define D 8
#define QS 12                // padded Q stride (floats) -> 48B, 16B-aligned
#define TWO_N 8192
#define HALF_N 4096
constexpr int BLOCK = 256;
constexpr int JC    = 32;    // j-chunk staged in LDS per block
constexpr int NTILE = 2176;  // sum_{b=0}^{15} (256 - 16b)
#define BOUNDARY (1.0f - 1e-5f)
#define LN2 0.6931471805599453f
#define TWO_LOG2E 2.8853900817779268f   // 2*log2(e)

typedef float f32x2 __attribute__((ext_vector_type(2)));

__device__ __forceinline__ float frcp(float x)  { return __builtin_amdgcn_rcpf(x); }
__device__ __forceinline__ float fsqrt(float x) { return __builtin_amdgcn_sqrtf(x); }
__device__ __forceinline__ float flog2(float x) { return __builtin_amdgcn_logf(x); }
__device__ __forceinline__ float fexp2(float x) { return __builtin_amdgcn_exp2f(x); }
__device__ __forceinline__ f32x2 splat(float v) { return (f32x2){v, v}; }

// ---- prep: Q[row] = [z(8), inv, inv*raw, 0, 0]; zero denom + out ----
__global__ __launch_bounds__(256) void prep_kernel(
    const float* __restrict__ zi, const float* __restrict__ zj,
    float* __restrict__ q, float* __restrict__ denom, float* __restrict__ out)
{
    const int row = blockIdx.x * 256 + threadIdx.x;
    const float* src = (row < HALF_N) ? (zi + (size_t)row * D)
                                      : (zj + (size_t)(row - HALF_N) * D);
    float4 a = *(const float4*)(src);
    float4 b = *(const float4*)(src + 4);
    float raw = a.x*a.x + a.y*a.y + a.z*a.z + a.w*a.w
              + b.x*b.x + b.y*b.y + b.z*b.z + b.w*b.w;
    float inv = frcp(1.0f - fminf(raw, BOUNDARY));
    float* dst = q + (size_t)row * QS;
    *(float4*)(dst)     = a;
    *(float4*)(dst + 4) = b;
    *(float4*)(dst + 8) = make_float4(inv, inv * raw, 0.0f, 0.0f);
    denom[row] = 0.0f;
    if (row == 0) out[0] = 0.0f;
}

// ---- symmetric pair kernel, packed tiles, packed-fp32 math ----
__global__ __launch_bounds__(BLOCK, 8) void pair_kernel(
    const float* __restrict__ q, float* __restrict__ denom)
{
    __shared__ float sq[JC * QS];       // 1.5 KB j-chunk Q
    __shared__ float sdenom[JC];        // column accumulators

    const int tid = threadIdx.x;

    // tile decode: t -> (b = i-block of 512 rows, jbase)
    const int t = blockIdx.x;
    int b = 0;
    #pragma unroll
    for (int k = 1; k < 16; ++k)
        b += (t >= (256 * k - 8 * k * (k - 1))) ? 1 : 0;
    const int Fb    = 256 * b - 8 * b * (b - 1);
    const int ibase = 512 * b;
    const int jbase = ibase + 32 * (t - Fb);
    const bool diag = (jbase < ibase + 512);

    // stage j-chunk Q (96 float4) + zero column accumulators
    if (tid < JC * QS / 4)
        ((float4*)sq)[tid] = ((const float4*)(q + (size_t)jbase * QS))[tid];
    if (tid < JC) sdenom[tid] = 0.0f;

    // own two rows -> packed P: p2[k] = {P_row0[k], P_row1[k]}
    const int irow0 = ibase + tid;
    const int irow1 = ibase + tid + BLOCK;
    f32x2 p2[10];
    {
        const float* q0 = q + (size_t)irow0 * QS;
        const float* q1 = q + (size_t)irow1 * QS;
        float4 a0 = *(const float4*)(q0), b0 = *(const float4*)(q0 + 4);
        float4 c0 = *(const float4*)(q0 + 8);
        float4 a1 = *(const float4*)(q1), b1 = *(const float4*)(q1 + 4);
        float4 c1 = *(const float4*)(q1 + 8);
        float m0 = -4.0f * c0.x, m1 = -4.0f * c1.x;
        p2[0] = (f32x2){m0 * a0.x, m1 * a1.x};
        p2[1] = (f32x2){m0 * a0.y, m1 * a1.y};
        p2[2] = (f32x2){m0 * a0.z, m1 * a1.z};
        p2[3] = (f32x2){m0 * a0.w, m1 * a1.w};
        p2[4] = (f32x2){m0 * b0.x, m1 * b1.x};
        p2[5] = (f32x2){m0 * b0.y, m1 * b1.y};
        p2[6] = (f32x2){m0 * b0.z, m1 * b1.z};
        p2[7] = (f32x2){m0 * b0.w, m1 * b1.w};
        p2[8] = (f32x2){2.0f * c0.y, 2.0f * c1.y};
        p2[9] = (f32x2){2.0f * c0.x, 2.0f * c1.x};
    }
    f32x2 acc2 = splat(0.0f);
    __syncthreads();

    #pragma unroll 4
    for (int jj = 0; jj < JC; ++jj) {
        const float* qq = sq + jj * QS;
        float4 a  = *(const float4*)(qq);         // broadcast, 16B-aligned
        float4 bb = *(const float4*)(qq + 4);
        float2 c  = *(const float2*)(qq + 8);
        const int j = jbase + jj;

        f32x2 x = splat(1.0f);
        x = __builtin_elementwise_fma(p2[0], splat(a.x),  x);
        x = __builtin_elementwise_fma(p2[1], splat(a.y),  x);
        x = __builtin_elementwise_fma(p2[2], splat(a.z),  x);
        x = __builtin_elementwise_fma(p2[3], splat(a.w),  x);
        x = __builtin_elementwise_fma(p2[4], splat(bb.x), x);
        x = __builtin_elementwise_fma(p2[5], splat(bb.y), x);
        x = __builtin_elementwise_fma(p2[6], splat(bb.z), x);
        x = __builtin_elementwise_fma(p2[7], splat(bb.w), x);
        x = __builtin_elementwise_fma(p2[8], splat(c.x),  x);
        x = __builtin_elementwise_fma(p2[9], splat(c.y),  x);

        f32x2 tt = __builtin_elementwise_fma(x, x, splat(-1.0f));
        tt = __builtin_elementwise_max(tt, splat(0.0f));
        f32x2 s  = (f32x2){fsqrt(tt.x), fsqrt(tt.y)};      // scalar trans x2
        f32x2 y  = x + s;
        f32x2 L  = (f32x2){flog2(y.x), flog2(y.y)};        // scalar trans x2
        f32x2 dd = __builtin_elementwise_fma(L, splat(LN2), splat(1.0f));
        f32x2 sim = (f32x2){frcp(dd.x), frcp(dd.y)};       // scalar trans x2
        f32x2 arg = sim * splat(TWO_LOG2E);
        f32x2 e  = (f32x2){fexp2(arg.x), fexp2(arg.y)};    // scalar trans x2

        if (diag) {
            e.x = (j > irow0) ? e.x : 0.0f;   // strict upper triangle
            e.y = (j > irow1) ? e.y : 0.0f;
        }
        acc2 += e;

        // wave reduction of column sum -> lane 0 -> LDS accumulate
        float ecol = e.x + e.y;
        #pragma unroll
        for (int m = 1; m < 64; m <<= 1)
            ecol += __shfl_xor(ecol, m, 64);
        if ((tid & 63) == 0) atomicAdd(&sdenom[jj], ecol);
    }

    __syncthreads();
    if (tid < JC) atomicAdd(&denom[jbase + tid], sdenom[tid]);
    atomicAdd(&denom[irow0], acc2.x);
    atomicAdd(&denom[irow1], acc2.y);
}

// ---- epilogue: 8 blocks x 1024, one row/thread; denom excludes self ----
__global__ __launch_bounds__(1024) void reduce_kernel(
    const float* __restrict__ zi, const float* __restrict__ zj,
    const float* __restrict__ denom, float* __restrict__ out)
{
    __shared__ float s_red[1024];
    const int tid = threadIdx.x;
    const int i   = blockIdx.x * 1024 + tid;

    const int base = (i < HALF_N) ? i : (i - HALF_N);
    const float* pa = (i < HALF_N) ? (zi + (size_t)base * D) : (zj + (size_t)base * D);
    const float* pb = (i < HALF_N) ? (zj + (size_t)base * D) : (zi + (size_t)base * D);
    float4 a0 = *(const float4*)(pa), a1 = *(const float4*)(pa + 4);
    float4 b0 = *(const float4*)(pb), b1 = *(const float4*)(pb + 4);
    float rawa = a0.x*a0.x + a0.y*a0.y + a0.z*a0.z + a0.w*a0.w
               + a1.x*a1.x + a1.y*a1.y + a1.z*a1.z + a1.w*a1.w;
    float rawb = b0.x*b0.x + b0.y*b0.y + b0.z*b0.z + b0.w*b0.w
               + b1.x*b1.x + b1.y*b1.y + b1.z*b1.z + b1.w*b1.w;
    float dot  = a0.x*b0.x + a0.y*b0.y + a0.z*b0.z + a0.w*b0.w
               + a1.x*b1.x + a1.y*b1.y + a1.z*b1.z + a1.w*b1.w;
    float sqd  = fmaxf(rawa + rawb - 2.0f * dot, 0.0f);
    float inva = frcp(1.0f - fminf(rawa, BOUNDARY));
    float invb = frcp(1.0f - fminf(rawb, BOUNDARY));
    float x    = fmaf(2.0f * sqd, inva * invb, 1.0f);
    float t    = fmaf(x, x, -1.0f);
    float s    = fsqrt(fmaxf(t, 0.0f));
    float dist = flog2(x + s) * LN2;
    float sim  = frcp(1.0f + dist);               // positive pair similarity
    float dlog = flog2(denom[i]) * LN2;           // self already excluded
    float term = -(2.0f * sim - dlog);

    s_red[tid] = term;
    __syncthreads();
    for (int off = 512; off > 0; off >>= 1) {
        if (tid < off) s_red[tid] += s_red[tid + off];
        __syncthreads();
    }
    if (tid == 0) atomicAdd(out, s_red[0] * (1.0f / (float)TWO_N));
}

extern "C" void kernel_launch(void* const* d_in, const int* in_sizes, int n_in,
                              void* d_out, int out_size, void* d_ws, size_t ws_size,
                              hipStream_t stream) {
    const float* zi = (const float*)d_in[0];
    const float* zj = (const float*)d_in[1];

    float* denom = (float*)d_ws;                  // [8192]
    float* q     = denom + TWO_N;                 // [8192 * 12]

    prep_kernel<<<TWO_N / 256, 256, 0, stream>>>(zi, zj, q, denom, (float*)d_out);

    pair_kernel<<<NTILE, BLOCK, 0, stream>>>(q, denom);

    reduce_kernel<<<TWO_N / 1024, 1024, 0, stream>>>(zi, zj, denom, (float*)d_out);
}